// Round 1
// baseline (964.948 us; speedup 1.0000x reference)
//
#include <hip/hip_runtime.h>
#include <hip/hip_bf16.h>

typedef unsigned int uint;
typedef unsigned short ushort;

// ---- problem constants ----
#define SCALAR_W 0.14433756729740643f   // 1/sqrt(3*16)
#define PW_CONST 0.13608276348795434f   // 1/sqrt(3*4*4.5)
#define RSQRT3   0.57735026918962576f   // attn2d scale

// ---- ws layout ----  total 6,414,336 bytes (unchanged)
// float-index offsets:
#define OFF_QS    0                     // [768][12][16] fp32  q*scalar_w
#define OFF_QP    147456                // [768][48][3] fp32   q points (global frame)
#define OFF_FINP  258048                // [768][576] fp32     final cols 0..575
// ushort-index offsets from ws base (HEAD-MAJOR layouts for coalesced tiles):
#define US_KC     1400832               // [12][768][28] bf16  (16 scalar K | 12 point K)
#define US_VS     1658880               // [12][768][16] bf16  scalar V
#define US_VP     1806336               // [12][768][24] bf16  point V
#define US_FA     2027520               // [768][1536] bf16    final cols 576..2111 (unchanged)

__device__ __forceinline__ float blo(uint u){ return __uint_as_float(u << 16); }
__device__ __forceinline__ float bhi(uint u){ return __uint_as_float(u & 0xffff0000u); }
__device__ __forceinline__ float bf1(ushort s){ return __uint_as_float(((uint)s) << 16); }
__device__ __forceinline__ ushort f2us(float f){
  return (ushort)__bfloat16_as_ushort(__float2bfloat16(f));
}

// ---------------- K1: projections + global-frame transform (fp32 inputs) ----------------
__global__ __launch_bounds__(256) void k_proj(
    const float* __restrict__ rot, const float* __restrict__ trans,
    const float* __restrict__ qsw, const float* __restrict__ qsb,
    const float* __restrict__ kvsw, const float* __restrict__ kvsb,
    const float* __restrict__ qpw, const float* __restrict__ qpb,
    const float* __restrict__ kvpw, const float* __restrict__ kvpb,
    const float* __restrict__ in1d, float* ws){
  __shared__ float orow[1152];
  __shared__ float rotL[9], transL[3];
  const int n = blockIdx.x, t = threadIdx.x;
  const float* arow = in1d + n*384;            // block-uniform -> s_load
  if (t < 9) rotL[t] = rot[n*9+t];
  if (t >= 9 && t < 12) transL[t-9] = trans[n*3+t-9];
  #pragma unroll
  for (int r = 0; r < 3; ++r){
    int idx = t + 256*r;
    if (idx < 576){
      int o = idx*2;
      const float* w; const float* bp; int ncol, col;
      if (o < 192){ w=qsw; ncol=192; col=o; bp=qsb+col; }
      else if (o < 576){ w=kvsw; ncol=384; col=o-192; bp=kvsb+col; }
      else if (o < 720){ w=qpw; ncol=144; col=o-576; bp=qpb+col; }
      else { w=kvpw; ncol=432; col=o-720; bp=kvpb+col; }
      float2 b2 = *reinterpret_cast<const float2*>(bp);   // col even -> 8B aligned
      float a0 = b2.x, a1 = b2.y;
      const float* wp = w + col;
      #pragma unroll 4
      for (int k = 0; k < 384; ++k){
        float2 u = *reinterpret_cast<const float2*>(wp + (size_t)k*ncol);
        float av = arow[k];
        a0 += av * u.x;
        a1 += av * u.y;
      }
      orow[o] = a0; orow[o+1] = a1;
    }
  }
  __syncthreads();
  float* qs_f = ws + OFF_QS;
  float* qp_f = ws + OFF_QP;
  ushort* ws16 = reinterpret_cast<ushort*>(ws);
  ushort* kC = ws16 + US_KC;
  ushort* vS = ws16 + US_VS;
  ushort* vP = ws16 + US_VP;
  if (t < 192) qs_f[n*192 + t] = orow[t] * SCALAR_W;
  for (int x = t; x < 384; x += 256){
    int h = x >> 5, d = x & 31;
    float v = orow[192 + x];
    if (d < 16) kC[((size_t)h*768 + n)*28 + d] = f2us(v);
    else        vS[((size_t)h*768 + n)*16 + (d-16)] = f2us(v);
  }
  for (int x = t; x < 144; x += 256){
    int d = x/3, c = x - 3*d;
    float g = rotL[c*3]*orow[576+d] + rotL[c*3+1]*orow[576+48+d] + rotL[c*3+2]*orow[576+96+d] + transL[c];
    qp_f[n*144 + d*3 + c] = g;
  }
  for (int x = t; x < 432; x += 256){
    int d = x/3, c = x - 3*d;
    float g = rotL[c*3]*orow[720+d] + rotL[c*3+1]*orow[720+144+d] + rotL[c*3+2]*orow[720+288+d] + transL[c];
    int h = d/12, pp = d - 12*h;
    if (pp < 4) kC[((size_t)h*768 + n)*28 + 16 + pp*3 + c] = f2us(g);
    else        vP[((size_t)h*768 + n)*24 + (pp-4)*3 + c] = f2us(g);
  }
}

// ---------------- K2: fused attention ----------------
// All hot loads are now COALESCED via per-wave LDS staging slices (896 dw each).
// Same-wave ds_write -> ds_read is in-order on CDNA: no extra __syncthreads().
__global__ __launch_bounds__(256) void k_attn(
    const float* __restrict__ in2d, const float* __restrict__ rot,
    const float* __restrict__ trans, const float* __restrict__ w2d,
    const float* __restrict__ b2d, const float* __restrict__ tpw,
    float* ws){
  __shared__ __align__(16) float Ld[768*12];    // 36,864 B logits/exp
  __shared__ __align__(16) float Sbuf[4*896];   // 14,336 B per-wave staging slices
  __shared__ float invL[12];
  __shared__ float pwS[12], b2S[12];
  __shared__ float rotL[9], transL[3];
  const int i = blockIdx.x, t = threadIdx.x;
  const int wv = t >> 6, ln = t & 63;
  const float* qs_f = ws + OFF_QS + i*192;     // block-uniform -> s_load
  const float* qp_f = ws + OFF_QP + i*144;
  const ushort* ws16 = reinterpret_cast<const ushort*>(ws);
  const ushort* kCp = ws16 + US_KC;
  const ushort* vSp = ws16 + US_VS;
  const ushort* vPp = ws16 + US_VP;
  float* slice = Sbuf + wv*896;                // this wave's private slice
  if (t < 9) rotL[t] = rot[i*9+t];
  if (t >= 9 && t < 12) transL[t-9] = trans[i*3+t-9];
  if (t < 12){
    b2S[t] = b2d[t];
    pwS[t] = -0.5f * PW_CONST * log1pf(__expf(tpw[t]));
  }
  __syncthreads();

  // ---- Phase A: logits (a2d + qk + point) ----
  for (int jg = 0; jg < 3; ++jg){
    const int j = jg*256 + t;                  // this thread's row
    const int rowbase = i*768 + jg*256 + wv*64;
    float acc12[12];
    #pragma unroll
    for (int h = 0; h < 12; ++h) acc12[h] = b2S[h];

    // --- a2d: 16 chunks x 8 fp32 channels, wave-local staging, prefetched ---
    const int r0 = ln >> 1, cq = (ln & 1)*4;
    const float* pA = in2d + (size_t)(rowbase + r0)*128 + cq;   // rows 0..31 of tile
    const float* pB = pA + 32*128;                              // rows 32..63
    float* wr0 = slice + r0*9 + cq;            // 9-dw pitch -> conflict-free reads
    float* wr1 = slice + (r0+32)*9 + cq;
    const float* rrow = slice + ln*9;
    float4 u0 = *reinterpret_cast<const float4*>(pA);
    float4 u1 = *reinterpret_cast<const float4*>(pB);
    // prefetch K head 0 now; latency hides under the whole a2d phase
    const uint4* kbase = reinterpret_cast<const uint4*>(kCp + ((size_t)jg*256 + wv*64)*28);
    uint4 k0 = kbase[ln], k1 = kbase[ln+64], k2 = kbase[ln+128];
    uint4 k3 = {0,0,0,0};
    if (ln < 32) k3 = kbase[ln+192];
    for (int cc = 0; cc < 16; ++cc){
      wr0[0]=u0.x; wr0[1]=u0.y; wr0[2]=u0.z; wr0[3]=u0.w;
      wr1[0]=u1.x; wr1[1]=u1.y; wr1[2]=u1.z; wr1[3]=u1.w;
      if (cc < 15){
        u0 = *reinterpret_cast<const float4*>(pA + (cc+1)*8);
        u1 = *reinterpret_cast<const float4*>(pB + (cc+1)*8);
      }
      __builtin_amdgcn_wave_barrier();
      #pragma unroll
      for (int c2 = 0; c2 < 8; ++c2){
        float x = rrow[c2];
        const float* wp = w2d + (cc*8 + c2)*12;  // lane-uniform -> s_load
        #pragma unroll
        for (int h = 0; h < 12; ++h) acc12[h] += x * wp[h];
      }
      __builtin_amdgcn_wave_barrier();
    }

    // --- scalar-K + point-K per head: 64-row x 56B tiles, wave-local staging ---
    uint4* dst = reinterpret_cast<uint4*>(slice);   // linear 14-dw rows
    #pragma unroll
    for (int h = 0; h < 12; ++h){
      dst[ln] = k0; dst[ln+64] = k1; dst[ln+128] = k2;
      if (ln < 32) dst[ln+192] = k3;
      if (h < 11){
        const uint4* nb = kbase + (size_t)(h+1)*2688;   // 768*28us = 2688 uint4 per head
        k0 = nb[ln]; k1 = nb[ln+64]; k2 = nb[ln+128];
        if (ln < 32) k3 = nb[ln+192];
      }
      __builtin_amdgcn_wave_barrier();
      const float* qr  = qs_f + h*16;          // uniform -> s_load
      const float* qpr = qp_f + h*12;          // uniform -> s_load
      const uint2* krow = reinterpret_cast<const uint2*>(slice + ln*14);  // 56B: 8B-aligned
      float qk = 0.f, d2 = 0.f;
      #pragma unroll
      for (int dd = 0; dd < 4; ++dd){
        uint2 u = krow[dd];
        qk += qr[4*dd]   * blo(u.x) + qr[4*dd+1] * bhi(u.x)
            + qr[4*dd+2] * blo(u.y) + qr[4*dd+3] * bhi(u.y);
      }
      #pragma unroll
      for (int e2 = 0; e2 < 3; ++e2){
        uint2 u = krow[4+e2];
        float d0 = qpr[4*e2]   - blo(u.x);
        float d1 = qpr[4*e2+1] - bhi(u.x);
        float db = qpr[4*e2+2] - blo(u.y);
        float d3 = qpr[4*e2+3] - bhi(u.y);
        d2 += d0*d0 + d1*d1 + db*db + d3*d3;
      }
      acc12[h] = acc12[h]*RSQRT3 + qk + pwS[h]*d2;
      __builtin_amdgcn_wave_barrier();
    }
    float4* lp = reinterpret_cast<float4*>(&Ld[j*12]);
    lp[0] = make_float4(acc12[0], acc12[1], acc12[2],  acc12[3]);
    lp[1] = make_float4(acc12[4], acc12[5], acc12[6],  acc12[7]);
    lp[2] = make_float4(acc12[8], acc12[9], acc12[10], acc12[11]);
  }
  __syncthreads();

  // ---- Phase B: wave wv owns heads {wv, wv+4, wv+8} (disjoint LDS columns) ----
  #pragma unroll
  for (int s = 0; s < 3; ++s){
    int h = wv + s*4;
    float m = -1e30f;
    for (int k = 0; k < 12; ++k) m = fmaxf(m, Ld[(ln + (k<<6))*12 + h]);
    #pragma unroll
    for (int o = 32; o > 0; o >>= 1) m = fmaxf(m, __shfl_xor(m, o));
    float sum = 0.f;
    for (int k = 0; k < 12; ++k){
      int idx = (ln + (k<<6))*12 + h;
      float e = __expf(fminf(Ld[idx] - m, 0.f));
      Ld[idx] = e;
      sum += e;
    }
    #pragma unroll
    for (int o = 32; o > 0; o >>= 1) sum += __shfl_xor(sum, o);
    if (ln == 0) invL[h] = 1.f / sum;
  }

  // ---- Phase C (same wave->head ownership; wave-local V staging, no barriers) ----
  float* finp = ws + OFF_FINP + (size_t)i*576;
  for (int s = 0; s < 3; ++s){
    const int h = wv + s*4;
    float accS[16], accP[24];
    #pragma unroll
    for (int d = 0; d < 16; ++d) accS[d] = 0.f;
    #pragma unroll
    for (int d = 0; d < 24; ++d) accP[d] = 0.f;
    // pass 1: scalar V (64-row x 32B tiles; 10-dw LDS pitch)
    {
      const uint4* vb = reinterpret_cast<const uint4*>(vSp + (size_t)h*768*16);
      uint4 a0 = vb[ln], a1 = vb[ln+64];
      const int r = ln >> 1, c = (ln & 1)*4;
      uint2* w0 = reinterpret_cast<uint2*>(slice + r*10 + c);
      uint2* w1 = reinterpret_cast<uint2*>(slice + (r+32)*10 + c);
      const uint2* vrow = reinterpret_cast<const uint2*>(slice + ln*10);
      for (int it = 0; it < 12; ++it){
        w0[0] = make_uint2(a0.x, a0.y); w0[1] = make_uint2(a0.z, a0.w);
        w1[0] = make_uint2(a1.x, a1.y); w1[1] = make_uint2(a1.z, a1.w);
        if (it < 11){
          const uint4* nb = vb + (size_t)(it+1)*128;
          a0 = nb[ln]; a1 = nb[ln+64];
        }
        __builtin_amdgcn_wave_barrier();
        float e = Ld[((it<<6) + ln)*12 + h];
        #pragma unroll
        for (int dd = 0; dd < 4; ++dd){
          uint2 u = vrow[dd];
          accS[4*dd]   += e * blo(u.x); accS[4*dd+1] += e * bhi(u.x);
          accS[4*dd+2] += e * blo(u.y); accS[4*dd+3] += e * bhi(u.y);
        }
        __builtin_amdgcn_wave_barrier();
      }
    }
    // pass 2: point V (64-row x 48B tiles; 14-dw LDS pitch)
    {
      const uint4* vb = reinterpret_cast<const uint4*>(vPp + (size_t)h*768*24);
      uint4 a0 = vb[ln], a1 = vb[ln+64], a2 = vb[ln+128];
      const int x1 = ln + 64, x2 = ln + 128;
      const int ra = (ln*171) >> 9,  ca = (ln - 3*ra)*4;   // x/3 exact for x<512
      const int rb = (x1*171) >> 9,  cb = (x1 - 3*rb)*4;
      const int rc = (x2*171) >> 9,  cx = (x2 - 3*rc)*4;
      uint2* w0 = reinterpret_cast<uint2*>(slice + ra*14 + ca);
      uint2* w1 = reinterpret_cast<uint2*>(slice + rb*14 + cb);
      uint2* w2 = reinterpret_cast<uint2*>(slice + rc*14 + cx);
      const uint2* vrow = reinterpret_cast<const uint2*>(slice + ln*14);
      for (int it = 0; it < 12; ++it){
        w0[0] = make_uint2(a0.x, a0.y); w0[1] = make_uint2(a0.z, a0.w);
        w1[0] = make_uint2(a1.x, a1.y); w1[1] = make_uint2(a1.z, a1.w);
        w2[0] = make_uint2(a2.x, a2.y); w2[1] = make_uint2(a2.z, a2.w);
        if (it < 11){
          const uint4* nb = vb + (size_t)(it+1)*192;
          a0 = nb[ln]; a1 = nb[ln+64]; a2 = nb[ln+128];
        }
        __builtin_amdgcn_wave_barrier();
        float e = Ld[((it<<6) + ln)*12 + h];
        #pragma unroll
        for (int dd = 0; dd < 6; ++dd){
          uint2 u = vrow[dd];
          accP[4*dd]   += e * blo(u.x); accP[4*dd+1] += e * bhi(u.x);
          accP[4*dd+2] += e * blo(u.y); accP[4*dd+3] += e * bhi(u.y);
        }
        __builtin_amdgcn_wave_barrier();
      }
    }
    #pragma unroll
    for (int o2 = 32; o2 > 0; o2 >>= 1){
      #pragma unroll
      for (int d = 0; d < 16; ++d) accS[d] += __shfl_xor(accS[d], o2);
      #pragma unroll
      for (int d = 0; d < 24; ++d) accP[d] += __shfl_xor(accP[d], o2);
    }
    if (ln == 0){
      float inv = invL[h];   // written by this same lane in Phase B
      #pragma unroll
      for (int d = 0; d < 16; ++d) finp[h*16 + d] = accS[d]*inv;
      #pragma unroll
      for (int p = 0; p < 8; ++p){
        float gx = accP[p*3+0]*inv - transL[0];
        float gy = accP[p*3+1]*inv - transL[1];
        float gz = accP[p*3+2]*inv - transL[2];
        float n2 = 1e-8f;
        #pragma unroll
        for (int c = 0; c < 3; ++c){
          float rr = rotL[c]*gx + rotL[3+c]*gy + rotL[6+c]*gz;  // rot^T
          finp[192 + c*96 + h*8 + p] = rr;
          n2 += rr*rr;
        }
        finp[480 + h*8 + p] = sqrtf(n2);
      }
    }
  }
  __syncthreads();   // all exp columns + invL visible everywhere
  // ---- Phase D: a_over_2d. thread = (channel pair cp, j-quarter jg) ----
  {
    const int cp = t & 63, jg = t >> 6;
    float acc[24];
    #pragma unroll
    for (int d = 0; d < 24; ++d) acc[d] = 0.f;
    const float* rowp = in2d + (size_t)i*768*128 + 2*cp;
    const int j0 = jg*192;
    for (int j = j0; j < j0 + 192; ++j){
      float2 x2 = *reinterpret_cast<const float2*>(rowp + (size_t)j*128);
      float x0 = x2.x, x1 = x2.y;
      const float4* lp = reinterpret_cast<const float4*>(&Ld[j*12]);  // wave-uniform -> broadcast
      float4 e0 = lp[0], e1 = lp[1], e2 = lp[2];
      acc[0] += e0.x*x0;  acc[1] += e0.x*x1;
      acc[2] += e0.y*x0;  acc[3] += e0.y*x1;
      acc[4] += e0.z*x0;  acc[5] += e0.z*x1;
      acc[6] += e0.w*x0;  acc[7] += e0.w*x1;
      acc[8] += e1.x*x0;  acc[9] += e1.x*x1;
      acc[10]+= e1.y*x0;  acc[11]+= e1.y*x1;
      acc[12]+= e1.z*x0;  acc[13]+= e1.z*x1;
      acc[14]+= e1.w*x0;  acc[15]+= e1.w*x1;
      acc[16]+= e2.x*x0;  acc[17]+= e2.x*x1;
      acc[18]+= e2.y*x0;  acc[19]+= e2.y*x1;
      acc[20]+= e2.z*x0;  acc[21]+= e2.z*x1;
      acc[22]+= e2.w*x0;  acc[23]+= e2.w*x1;
    }
    __syncthreads();   // all Ld reads done; reuse as reduction scratch
    float* LdR = Ld;   // [3][64][25] = 4800 floats < 9216
    if (jg > 0){
      #pragma unroll
      for (int d = 0; d < 24; ++d) LdR[((jg-1)*64 + cp)*25 + d] = acc[d];
    }
    __syncthreads();
    if (jg == 0){
      ushort* fa16 = reinterpret_cast<ushort*>(ws) + US_FA + (size_t)i*1536;
      float invA[12];
      #pragma unroll
      for (int h = 0; h < 12; ++h) invA[h] = invL[h];
      #pragma unroll
      for (int h = 0; h < 12; ++h){
        float a0 = acc[2*h]   + LdR[cp*25 + 2*h]   + LdR[(64+cp)*25 + 2*h]   + LdR[(128+cp)*25 + 2*h];
        float a1 = acc[2*h+1] + LdR[cp*25 + 2*h+1] + LdR[(64+cp)*25 + 2*h+1] + LdR[(128+cp)*25 + 2*h+1];
        fa16[h*128 + 2*cp]     = f2us(a0 * invA[h]);
        fa16[h*128 + 2*cp + 1] = f2us(a1 * invA[h]);
      }
    }
  }
}

// ---------------- K3: output GEMM (768x2112 @ 2112x384, fp32 out) ----------------
__global__ __launch_bounds__(128) void k_out(const float* __restrict__ out_w,
                                             const float* __restrict__ out_b,
                                             const float* ws,
                                             float* __restrict__ out){
  __shared__ float Arow[4*2112];   // 33,792 B
  const int o = blockIdx.x*128 + threadIdx.x;
  const int ib = blockIdx.y*4;
  const ushort* ws16 = reinterpret_cast<const ushort*>(ws);
  #pragma unroll
  for (int r = 0; r < 4; ++r){
    const float* fp = ws + OFF_FINP + (size_t)(ib+r)*576;
    for (int k = threadIdx.x; k < 576; k += 128) Arow[r*2112 + k] = fp[k];
    const ushort* fa = ws16 + US_FA + (size_t)(ib+r)*1536;
    for (int k = threadIdx.x; k < 1536; k += 128) Arow[r*2112 + 576 + k] = bf1(fa[k]);
  }
  __syncthreads();
  float bc = out_b[o];
  float acc0 = bc, acc1 = bc, acc2 = bc, acc3 = bc;
  const float* wp = out_w + o;
  #pragma unroll 8
  for (int k = 0; k < 2112; ++k){
    float w = wp[(size_t)k*384];
    acc0 += Arow[k]*w; acc1 += Arow[2112+k]*w; acc2 += Arow[4224+k]*w; acc3 += Arow[6336+k]*w;
  }
  // diagnostic sanitize: NaN/Inf -> 1e6 sentinel (never triggers when healthy)
  if (!(fabsf(acc0) < 1e30f)) acc0 = 1e6f;
  if (!(fabsf(acc1) < 1e30f)) acc1 = 1e6f;
  if (!(fabsf(acc2) < 1e30f)) acc2 = 1e6f;
  if (!(fabsf(acc3) < 1e30f)) acc3 = 1e6f;
  out[(ib+0)*384 + o] = acc0;
  out[(ib+1)*384 + o] = acc1;
  out[(ib+2)*384 + o] = acc2;
  out[(ib+3)*384 + o] = acc3;
}

extern "C" void kernel_launch(void* const* d_in, const int* in_sizes, int n_in,
                              void* d_out, int out_size, void* d_ws, size_t ws_size,
                              hipStream_t stream){
  const float* in1d  = (const float*)d_in[0];
  const float* in2d  = (const float*)d_in[1];
  const float* rot   = (const float*)d_in[2];
  const float* trans = (const float*)d_in[3];
  const float* qsw   = (const float*)d_in[4];
  const float* qsb   = (const float*)d_in[5];
  const float* kvsw  = (const float*)d_in[6];
  const float* kvsb  = (const float*)d_in[7];
  const float* qpw   = (const float*)d_in[8];
  const float* qpb   = (const float*)d_in[9];
  const float* kvpw  = (const float*)d_in[10];
  const float* kvpb  = (const float*)d_in[11];
  const float* tpw   = (const float*)d_in[12];
  const float* w2d   = (const float*)d_in[13];
  const float* b2d   = (const float*)d_in[14];
  const float* outw  = (const float*)d_in[15];
  const float* outb  = (const float*)d_in[16];
  float* ws = (float*)d_ws;

  k_proj<<<dim3(768), dim3(256), 0, stream>>>(rot, trans, qsw, qsb, kvsw, kvsb,
                                              qpw, qpb, kvpw, kvpb, in1d, ws);
  k_attn<<<dim3(768), dim3(256), 0, stream>>>(in2d, rot, trans, w2d, b2d, tpw, ws);
  k_out<<<dim3(3,192), dim3(128), 0, stream>>>(outw, outb, ws, (float*)d_out);
}

// Round 2
// 876.825 us; speedup vs baseline: 1.1005x; 1.1005x over previous
//
#include <hip/hip_runtime.h>
#include <hip/hip_bf16.h>

typedef unsigned int uint;
typedef unsigned short ushort;

// ---- problem constants ----
#define SCALAR_W 0.14433756729740643f   // 1/sqrt(3*16)
#define PW_CONST 0.13608276348795434f   // 1/sqrt(3*4*4.5)
#define RSQRT3   0.57735026918962576f   // attn2d scale

// ---- ws layout ----  total 6,414,336 bytes (~6.4 MB)  [round-0 layout]
// float-index offsets:
#define OFF_QS    0                     // [768][12][16] fp32  q*scalar_w
#define OFF_QP    147456                // [768][48][3] fp32   q points (global frame)
#define OFF_FINP  258048                // [768][576] fp32     final cols 0..575 (scalar|rpl|pnorm)
#define FLOAT_END 700416
// ushort-index offsets from ws base:
#define US_KS     1400832               // [768][12][16] bf16
#define US_VS     1548288               // [768][12][16] bf16
#define US_KP     1695744               // [768][12][4][3] bf16
#define US_VP     1806336               // [768][12][8][3] bf16
#define US_FA     2027520               // [768][1536] bf16    final cols 576..2111 (a_over_2d)

__device__ __forceinline__ float blo(uint u){ return __uint_as_float(u << 16); }
__device__ __forceinline__ float bhi(uint u){ return __uint_as_float(u & 0xffff0000u); }
__device__ __forceinline__ float bf1(ushort s){ return __uint_as_float(((uint)s) << 16); }
__device__ __forceinline__ void up8(uint4 u, float* f){
  f[0]=blo(u.x); f[1]=bhi(u.x); f[2]=blo(u.y); f[3]=bhi(u.y);
  f[4]=blo(u.z); f[5]=bhi(u.z); f[6]=blo(u.w); f[7]=bhi(u.w);
}
__device__ __forceinline__ ushort f2us(float f){
  return (ushort)__bfloat16_as_ushort(__float2bfloat16(f));
}

// ---------------- K1: projections + global-frame transform ----------------
// 4 n-rows per block: each weight float2 is reused 8x (4 rows x 2 cols).
// Weight L2 traffic: 1.36 GB -> 340 MB.  Input rows stay block-uniform
// global pointers -> scalar-pipe loads.
__global__ __launch_bounds__(256) void k_proj(
    const float* __restrict__ rot, const float* __restrict__ trans,
    const float* __restrict__ qsw, const float* __restrict__ qsb,
    const float* __restrict__ kvsw, const float* __restrict__ kvsb,
    const float* __restrict__ qpw, const float* __restrict__ qpb,
    const float* __restrict__ kvpw, const float* __restrict__ kvpb,
    const float* __restrict__ in1d, float* ws){
  __shared__ float orow[4*1152];          // 18,432 B
  __shared__ float rotL[4*9], transL[4*3];
  const int n0 = blockIdx.x*4, t = threadIdx.x;
  const float* arow0 = in1d + (size_t)(n0+0)*384;   // block-uniform -> s_load
  const float* arow1 = in1d + (size_t)(n0+1)*384;
  const float* arow2 = in1d + (size_t)(n0+2)*384;
  const float* arow3 = in1d + (size_t)(n0+3)*384;
  if (t < 36) rotL[t] = rot[n0*9 + t];
  if (t >= 36 && t < 48) transL[t-36] = trans[n0*3 + (t-36)];
  #pragma unroll
  for (int r2 = 0; r2 < 3; ++r2){
    int idx = t + 256*r2;
    if (idx < 576){
      int o = idx*2;
      const float* w; const float* bp; int ncol, col;
      if (o < 192){ w=qsw; ncol=192; col=o; bp=qsb+col; }
      else if (o < 576){ w=kvsw; ncol=384; col=o-192; bp=kvsb+col; }
      else if (o < 720){ w=qpw; ncol=144; col=o-576; bp=qpb+col; }
      else { w=kvpw; ncol=432; col=o-720; bp=kvpb+col; }
      float2 b2 = *reinterpret_cast<const float2*>(bp);   // col even -> 8B aligned
      float a00 = b2.x, a01 = b2.y;
      float a10 = b2.x, a11 = b2.y;
      float a20 = b2.x, a21 = b2.y;
      float a30 = b2.x, a31 = b2.y;
      const float* wp = w + col;
      #pragma unroll 4
      for (int k = 0; k < 384; ++k){
        float2 u = *reinterpret_cast<const float2*>(wp + (size_t)k*ncol);
        float x0 = arow0[k], x1 = arow1[k], x2 = arow2[k], x3 = arow3[k];
        a00 += x0*u.x; a01 += x0*u.y;
        a10 += x1*u.x; a11 += x1*u.y;
        a20 += x2*u.x; a21 += x2*u.y;
        a30 += x3*u.x; a31 += x3*u.y;
      }
      orow[o]          = a00; orow[o+1]          = a01;
      orow[1152 + o]   = a10; orow[1152 + o+1]   = a11;
      orow[2*1152 + o] = a20; orow[2*1152 + o+1] = a21;
      orow[3*1152 + o] = a30; orow[3*1152 + o+1] = a31;
    }
  }
  __syncthreads();
  float* qs_f = ws + OFF_QS;
  float* qp_f = ws + OFF_QP;
  ushort* ws16 = reinterpret_cast<ushort*>(ws);
  ushort* kS = ws16 + US_KS;
  ushort* vS = ws16 + US_VS;
  ushort* kP = ws16 + US_KP;
  ushort* vP = ws16 + US_VP;
  #pragma unroll
  for (int r = 0; r < 4; ++r){
    const int n = n0 + r;
    const float* od = orow + r*1152;
    const float* rL = rotL + r*9;
    const float* tL = transL + r*3;
    if (t < 192) qs_f[n*192 + t] = od[t] * SCALAR_W;
    for (int x = t; x < 384; x += 256){
      int h = x >> 5, d = x & 31;
      float v = od[192 + x];
      if (d < 16) kS[(n*12 + h)*16 + d] = f2us(v);
      else        vS[(n*12 + h)*16 + (d-16)] = f2us(v);
    }
    for (int x = t; x < 144; x += 256){
      int d = x/3, c = x - 3*d;
      float g = rL[c*3]*od[576+d] + rL[c*3+1]*od[576+48+d] + rL[c*3+2]*od[576+96+d] + tL[c];
      qp_f[n*144 + d*3 + c] = g;
    }
    for (int x = t; x < 432; x += 256){
      int d = x/3, c = x - 3*d;
      float g = rL[c*3]*od[720+d] + rL[c*3+1]*od[720+144+d] + rL[c*3+2]*od[720+288+d] + tL[c];
      int h = d/12, pp = d - 12*h;
      if (pp < 4) kP[((n*12+h)*4 + pp)*3 + c] = f2us(g);
      else        vP[((n*12+h)*8 + (pp-4))*3 + c] = f2us(g);
    }
  }
}

// ---------------- K2: fused attention (round-0 exact) ----------------
// Phase A: logits (qk + point + a2d) -> LDS [j][12]
// Phase B: per-head softmax (exp in-place, 1/sum)
// Phase C: scalar + point contractions -> FINP fp32
// Phase D: a_over_2d -> FA bf16
__global__ __launch_bounds__(256) void k_attn(
    const float* __restrict__ in2d, const float* __restrict__ rot,
    const float* __restrict__ trans, const float* __restrict__ w2d,
    const float* __restrict__ b2d, const float* __restrict__ tpw,
    float* ws){
  __shared__ __align__(16) float Ld[768*12];   // 36,864 B
  __shared__ float invL[12];
  __shared__ float pwS[12], b2S[12];
  __shared__ float rotL[9], transL[3];
  const int i = blockIdx.x, t = threadIdx.x;
  const float* qs_f = ws + OFF_QS + i*192;     // block-uniform -> s_load
  const float* qp_f = ws + OFF_QP + i*144;
  const ushort* ws16 = reinterpret_cast<const ushort*>(ws);
  const ushort* kSp = ws16 + US_KS;
  const ushort* vSp = ws16 + US_VS;
  const ushort* kPp = ws16 + US_KP;
  const ushort* vPp = ws16 + US_VP;
  if (t < 9) rotL[t] = rot[i*9+t];
  if (t >= 9 && t < 12) transL[t-9] = trans[i*3+t-9];
  if (t < 12){
    b2S[t] = b2d[t];
    pwS[t] = -0.5f * PW_CONST * log1pf(__expf(tpw[t]));
  }
  __syncthreads();
  // ---- Phase A ----
  for (int j = t; j < 768; j += 256){
    float acc12[12];
    #pragma unroll
    for (int h = 0; h < 12; ++h) acc12[h] = b2S[h];
    const float4* p2 = reinterpret_cast<const float4*>(in2d + (size_t)(i*768 + j)*128);
    #pragma unroll 4
    for (int c4 = 0; c4 < 32; ++c4){
      float4 u = p2[c4];
      const float* wr = w2d + c4*48;           // lane-uniform -> scalar loads
      #pragma unroll
      for (int h = 0; h < 12; ++h)
        acc12[h] += u.x*wr[h] + u.y*wr[12+h] + u.z*wr[24+h] + u.w*wr[36+h];
    }
    #pragma unroll
    for (int h = 0; h < 12; ++h){
      const uint4* pk = reinterpret_cast<const uint4*>(kSp + ((size_t)j*12 + h)*16);
      uint4 a = pk[0], b = pk[1];
      float kf[16]; up8(a, kf); up8(b, kf+8);
      float qk = 0.f;
      const float* qr = qs_f + h*16;           // uniform
      #pragma unroll
      for (int d = 0; d < 16; ++d) qk += qr[d] * kf[d];
      const uint2* pp = reinterpret_cast<const uint2*>(kPp + ((size_t)j*12 + h)*12);
      uint2 c0 = pp[0], c1 = pp[1], c2 = pp[2];
      float pf[12] = {blo(c0.x),bhi(c0.x),blo(c0.y),bhi(c0.y),
                      blo(c1.x),bhi(c1.x),blo(c1.y),bhi(c1.y),
                      blo(c2.x),bhi(c2.x),blo(c2.y),bhi(c2.y)};
      const float* qpr = qp_f + h*12;          // uniform
      float d2 = 0.f;
      #pragma unroll
      for (int e = 0; e < 12; ++e){ float dd = qpr[e] - pf[e]; d2 += dd*dd; }
      acc12[h] = acc12[h]*RSQRT3 + qk + pwS[h]*d2;
    }
    float4* lp = reinterpret_cast<float4*>(&Ld[j*12]);
    lp[0] = make_float4(acc12[0], acc12[1], acc12[2],  acc12[3]);
    lp[1] = make_float4(acc12[4], acc12[5], acc12[6],  acc12[7]);
    lp[2] = make_float4(acc12[8], acc12[9], acc12[10], acc12[11]);
  }
  __syncthreads();
  // ---- Phase B: wave w owns heads {w, w+4, w+8} (disjoint LDS columns) ----
  const int wave = t >> 6, lane = t & 63;
  float invReg[3];
  #pragma unroll
  for (int s = 0; s < 3; ++s){
    int h = wave + s*4;
    float m = -1e30f;
    for (int k = 0; k < 12; ++k) m = fmaxf(m, Ld[(lane + (k<<6))*12 + h]);
    #pragma unroll
    for (int o = 32; o > 0; o >>= 1) m = fmaxf(m, __shfl_xor(m, o));
    float sum = 0.f;
    for (int k = 0; k < 12; ++k){
      int idx = (lane + (k<<6))*12 + h;
      float e = __expf(fminf(Ld[idx] - m, 0.f));
      Ld[idx] = e;
      sum += e;
    }
    #pragma unroll
    for (int o = 32; o > 0; o >>= 1) sum += __shfl_xor(sum, o);
    float inv = 1.f / sum;
    invReg[s] = inv;
    if (lane == 0) invL[h] = inv;
  }
  // ---- Phase C (same wave->head ownership; no barrier needed) ----
  float* finp = ws + OFF_FINP + (size_t)i*576;
  #pragma unroll
  for (int s = 0; s < 3; ++s){
    int h = wave + s*4;
    float accS[16], accP[24];
    #pragma unroll
    for (int d = 0; d < 16; ++d) accS[d] = 0.f;
    #pragma unroll
    for (int d = 0; d < 24; ++d) accP[d] = 0.f;
    for (int it = 0; it < 12; ++it){
      int jj = lane + (it<<6);
      float e = Ld[jj*12 + h];
      const uint4* pv = reinterpret_cast<const uint4*>(vSp + ((size_t)jj*12 + h)*16);
      uint4 a = pv[0], b = pv[1];
      float vf[16]; up8(a, vf); up8(b, vf+8);
      #pragma unroll
      for (int d = 0; d < 16; ++d) accS[d] += e * vf[d];
      const uint4* pq = reinterpret_cast<const uint4*>(vPp + ((size_t)jj*12 + h)*24);
      uint4 q0 = pq[0], q1 = pq[1], q2 = pq[2];
      float pf[24]; up8(q0, pf); up8(q1, pf+8); up8(q2, pf+16);
      #pragma unroll
      for (int d = 0; d < 24; ++d) accP[d] += e * pf[d];
    }
    #pragma unroll
    for (int o2 = 32; o2 > 0; o2 >>= 1){
      #pragma unroll
      for (int d = 0; d < 16; ++d) accS[d] += __shfl_xor(accS[d], o2);
      #pragma unroll
      for (int d = 0; d < 24; ++d) accP[d] += __shfl_xor(accP[d], o2);
    }
    if (lane == 0){
      float inv = invReg[s];
      #pragma unroll
      for (int d = 0; d < 16; ++d) finp[h*16 + d] = accS[d]*inv;
      #pragma unroll
      for (int p = 0; p < 8; ++p){
        float gx = accP[p*3+0]*inv - transL[0];
        float gy = accP[p*3+1]*inv - transL[1];
        float gz = accP[p*3+2]*inv - transL[2];
        float n2 = 1e-8f;
        #pragma unroll
        for (int c = 0; c < 3; ++c){
          float r = rotL[c]*gx + rotL[3+c]*gy + rotL[6+c]*gz;  // rot^T
          finp[192 + c*96 + h*8 + p] = r;
          n2 += r*r;
        }
        finp[480 + h*8 + p] = sqrtf(n2);
      }
    }
  }
  __syncthreads();   // all exp columns + invL visible everywhere
  // ---- Phase D: a_over_2d. thread = (channel pair cp, j-quarter jg) ----
  {
    const int cp = t & 63, jg = t >> 6;
    float acc[24];
    #pragma unroll
    for (int d = 0; d < 24; ++d) acc[d] = 0.f;
    const float* rowp = in2d + (size_t)i*768*128 + 2*cp;
    const int j0 = jg*192;
    for (int j = j0; j < j0 + 192; ++j){
      float2 x2 = *reinterpret_cast<const float2*>(rowp + (size_t)j*128);
      float x0 = x2.x, x1 = x2.y;
      const float4* lp = reinterpret_cast<const float4*>(&Ld[j*12]);  // wave-uniform -> broadcast
      float4 e0 = lp[0], e1 = lp[1], e2 = lp[2];
      acc[0] += e0.x*x0;  acc[1] += e0.x*x1;
      acc[2] += e0.y*x0;  acc[3] += e0.y*x1;
      acc[4] += e0.z*x0;  acc[5] += e0.z*x1;
      acc[6] += e0.w*x0;  acc[7] += e0.w*x1;
      acc[8] += e1.x*x0;  acc[9] += e1.x*x1;
      acc[10]+= e1.y*x0;  acc[11]+= e1.y*x1;
      acc[12]+= e1.z*x0;  acc[13]+= e1.z*x1;
      acc[14]+= e1.w*x0;  acc[15]+= e1.w*x1;
      acc[16]+= e2.x*x0;  acc[17]+= e2.x*x1;
      acc[18]+= e2.y*x0;  acc[19]+= e2.y*x1;
      acc[20]+= e2.z*x0;  acc[21]+= e2.z*x1;
      acc[22]+= e2.w*x0;  acc[23]+= e2.w*x1;
    }
    __syncthreads();   // all Ld reads done; reuse as reduction scratch
    float* LdR = Ld;   // [3][64][25] = 4800 floats < 9216
    if (jg > 0){
      #pragma unroll
      for (int d = 0; d < 24; ++d) LdR[((jg-1)*64 + cp)*25 + d] = acc[d];
    }
    __syncthreads();
    if (jg == 0){
      ushort* fa16 = reinterpret_cast<ushort*>(ws) + US_FA + (size_t)i*1536;
      float invA[12];
      #pragma unroll
      for (int h = 0; h < 12; ++h) invA[h] = invL[h];
      #pragma unroll
      for (int h = 0; h < 12; ++h){
        float a0 = acc[2*h]   + LdR[cp*25 + 2*h]   + LdR[(64+cp)*25 + 2*h]   + LdR[(128+cp)*25 + 2*h];
        float a1 = acc[2*h+1] + LdR[cp*25 + 2*h+1] + LdR[(64+cp)*25 + 2*h+1] + LdR[(128+cp)*25 + 2*h+1];
        fa16[h*128 + 2*cp]     = f2us(a0 * invA[h]);
        fa16[h*128 + 2*cp + 1] = f2us(a1 * invA[h]);
      }
    }
  }
}

// ---------------- K3: output GEMM (768x2112 @ 2112x384, fp32 out) ----------------
__global__ __launch_bounds__(128) void k_out(const float* __restrict__ out_w,
                                             const float* __restrict__ out_b,
                                             const float* ws,
                                             float* __restrict__ out){
  __shared__ float Arow[4*2112];   // 33,792 B
  const int o = blockIdx.x*128 + threadIdx.x;
  const int ib = blockIdx.y*4;
  const ushort* ws16 = reinterpret_cast<const ushort*>(ws);
  #pragma unroll
  for (int r = 0; r < 4; ++r){
    const float* fp = ws + OFF_FINP + (size_t)(ib+r)*576;
    for (int k = threadIdx.x; k < 576; k += 128) Arow[r*2112 + k] = fp[k];
    const ushort* fa = ws16 + US_FA + (size_t)(ib+r)*1536;
    for (int k = threadIdx.x; k < 1536; k += 128) Arow[r*2112 + 576 + k] = bf1(fa[k]);
  }
  __syncthreads();
  float bc = out_b[o];
  float acc0 = bc, acc1 = bc, acc2 = bc, acc3 = bc;
  const float* wp = out_w + o;
  #pragma unroll 8
  for (int k = 0; k < 2112; ++k){
    float w = wp[(size_t)k*384];
    acc0 += Arow[k]*w; acc1 += Arow[2112+k]*w; acc2 += Arow[4224+k]*w; acc3 += Arow[6336+k]*w;
  }
  // diagnostic sanitize: NaN/Inf -> 1e6 sentinel (never triggers when healthy)
  if (!(fabsf(acc0) < 1e30f)) acc0 = 1e6f;
  if (!(fabsf(acc1) < 1e30f)) acc1 = 1e6f;
  if (!(fabsf(acc2) < 1e30f)) acc2 = 1e6f;
  if (!(fabsf(acc3) < 1e30f)) acc3 = 1e6f;
  out[(ib+0)*384 + o] = acc0;
  out[(ib+1)*384 + o] = acc1;
  out[(ib+2)*384 + o] = acc2;
  out[(ib+3)*384 + o] = acc3;
}

extern "C" void kernel_launch(void* const* d_in, const int* in_sizes, int n_in,
                              void* d_out, int out_size, void* d_ws, size_t ws_size,
                              hipStream_t stream){
  const float* in1d  = (const float*)d_in[0];
  const float* in2d  = (const float*)d_in[1];
  const float* rot   = (const float*)d_in[2];
  const float* trans = (const float*)d_in[3];
  const float* qsw   = (const float*)d_in[4];
  const float* qsb   = (const float*)d_in[5];
  const float* kvsw  = (const float*)d_in[6];
  const float* kvsb  = (const float*)d_in[7];
  const float* qpw   = (const float*)d_in[8];
  const float* qpb   = (const float*)d_in[9];
  const float* kvpw  = (const float*)d_in[10];
  const float* kvpb  = (const float*)d_in[11];
  const float* tpw   = (const float*)d_in[12];
  const float* w2d   = (const float*)d_in[13];
  const float* b2d   = (const float*)d_in[14];
  const float* outw  = (const float*)d_in[15];
  const float* outb  = (const float*)d_in[16];
  float* ws = (float*)d_ws;

  k_proj<<<dim3(192), dim3(256), 0, stream>>>(rot, trans, qsw, qsb, kvsw, kvsb,
                                              qpw, qpb, kvpw, kvpb, in1d, ws);
  k_attn<<<dim3(768), dim3(256), 0, stream>>>(in2d, rot, trans, w2d, b2d, tpw, ws);
  k_out<<<dim3(3,192), dim3(128), 0, stream>>>(outw, outb, ws, (float*)d_out);
}

// Round 4
// 853.838 us; speedup vs baseline: 1.1301x; 1.0269x over previous
//
#include <hip/hip_runtime.h>
#include <hip/hip_bf16.h>

typedef unsigned int uint;
typedef unsigned short ushort;

// ---- problem constants ----
#define SCALAR_W 0.14433756729740643f   // 1/sqrt(3*16)
#define PW_CONST 0.13608276348795434f   // 1/sqrt(3*4*4.5)
#define RSQRT3   0.57735026918962576f   // attn2d scale

// ---- ws layout ----  total 6,414,336 bytes (same footprint as round-0)
// float-index offsets:
#define OFF_QS    0                     // [768][12][16] fp32  q*scalar_w
#define OFF_QP    147456                // [768][48][3] fp32   q points (global frame)
#define OFF_FINP  258048                // [768][576] fp32     final cols 0..575 (scalar|rpl|pnorm)
// ushort-index offsets from ws base (HEAD-MAJOR: lane j reads contiguous rows):
#define US_KS     1400832               // [12][768][16] bf16  scalar K
#define US_VS     1548288               // [12][768][16] bf16  scalar V
#define US_KP     1695744               // [12][768][12] bf16  point K
#define US_VP     1806336               // [12][768][24] bf16  point V
#define US_FA     2027520               // [768][1536] bf16    final cols 576..2111 (a_over_2d)

__device__ __forceinline__ float blo(uint u){ return __uint_as_float(u << 16); }
__device__ __forceinline__ float bhi(uint u){ return __uint_as_float(u & 0xffff0000u); }
__device__ __forceinline__ float bf1(ushort s){ return __uint_as_float(((uint)s) << 16); }
__device__ __forceinline__ void up8(uint4 u, float* f){
  f[0]=blo(u.x); f[1]=bhi(u.x); f[2]=blo(u.y); f[3]=bhi(u.y);
  f[4]=blo(u.z); f[5]=bhi(u.z); f[6]=blo(u.w); f[7]=bhi(u.w);
}
__device__ __forceinline__ ushort f2us(float f){
  return (ushort)__bfloat16_as_ushort(__float2bfloat16(f));
}

// ---------------- K1: projections + global-frame transform ----------------
// 4 n-rows per block (8x weight reuse). Writes K/V tables HEAD-MAJOR.
__global__ __launch_bounds__(256) void k_proj(
    const float* __restrict__ rot, const float* __restrict__ trans,
    const float* __restrict__ qsw, const float* __restrict__ qsb,
    const float* __restrict__ kvsw, const float* __restrict__ kvsb,
    const float* __restrict__ qpw, const float* __restrict__ qpb,
    const float* __restrict__ kvpw, const float* __restrict__ kvpb,
    const float* __restrict__ in1d, float* ws){
  __shared__ float orow[4*1152];          // 18,432 B
  __shared__ float rotL[4*9], transL[4*3];
  const int n0 = blockIdx.x*4, t = threadIdx.x;
  const float* arow0 = in1d + (size_t)(n0+0)*384;   // block-uniform -> s_load
  const float* arow1 = in1d + (size_t)(n0+1)*384;
  const float* arow2 = in1d + (size_t)(n0+2)*384;
  const float* arow3 = in1d + (size_t)(n0+3)*384;
  if (t < 36) rotL[t] = rot[n0*9 + t];
  if (t >= 36 && t < 48) transL[t-36] = trans[n0*3 + (t-36)];
  #pragma unroll
  for (int r2 = 0; r2 < 3; ++r2){
    int idx = t + 256*r2;
    if (idx < 576){
      int o = idx*2;
      const float* w; const float* bp; int ncol, col;
      if (o < 192){ w=qsw; ncol=192; col=o; bp=qsb+col; }
      else if (o < 576){ w=kvsw; ncol=384; col=o-192; bp=kvsb+col; }
      else if (o < 720){ w=qpw; ncol=144; col=o-576; bp=qpb+col; }
      else { w=kvpw; ncol=432; col=o-720; bp=kvpb+col; }
      float2 b2 = *reinterpret_cast<const float2*>(bp);   // col even -> 8B aligned
      float a00 = b2.x, a01 = b2.y;
      float a10 = b2.x, a11 = b2.y;
      float a20 = b2.x, a21 = b2.y;
      float a30 = b2.x, a31 = b2.y;
      const float* wp = w + col;
      #pragma unroll 4
      for (int k = 0; k < 384; ++k){
        float2 u = *reinterpret_cast<const float2*>(wp + (size_t)k*ncol);
        float x0 = arow0[k], x1 = arow1[k], x2 = arow2[k], x3 = arow3[k];
        a00 += x0*u.x; a01 += x0*u.y;
        a10 += x1*u.x; a11 += x1*u.y;
        a20 += x2*u.x; a21 += x2*u.y;
        a30 += x3*u.x; a31 += x3*u.y;
      }
      orow[o]          = a00; orow[o+1]          = a01;
      orow[1152 + o]   = a10; orow[1152 + o+1]   = a11;
      orow[2*1152 + o] = a20; orow[2*1152 + o+1] = a21;
      orow[3*1152 + o] = a30; orow[3*1152 + o+1] = a31;
    }
  }
  __syncthreads();
  float* qs_f = ws + OFF_QS;
  float* qp_f = ws + OFF_QP;
  ushort* ws16 = reinterpret_cast<ushort*>(ws);
  ushort* kS = ws16 + US_KS;
  ushort* vS = ws16 + US_VS;
  ushort* kP = ws16 + US_KP;
  ushort* vP = ws16 + US_VP;
  #pragma unroll
  for (int r = 0; r < 4; ++r){
    const int n = n0 + r;
    const float* od = orow + r*1152;
    const float* rL = rotL + r*9;
    const float* tL = transL + r*3;
    if (t < 192) qs_f[n*192 + t] = od[t] * SCALAR_W;
    for (int x = t; x < 384; x += 256){
      int h = x >> 5, d = x & 31;
      float v = od[192 + x];
      if (d < 16) kS[((size_t)h*768 + n)*16 + d] = f2us(v);
      else        vS[((size_t)h*768 + n)*16 + (d-16)] = f2us(v);
    }
    for (int x = t; x < 144; x += 256){
      int d = x/3, c = x - 3*d;
      float g = rL[c*3]*od[576+d] + rL[c*3+1]*od[576+48+d] + rL[c*3+2]*od[576+96+d] + tL[c];
      qp_f[n*144 + d*3 + c] = g;
    }
    for (int x = t; x < 432; x += 256){
      int d = x/3, c = x - 3*d;
      float g = rL[c*3]*od[720+d] + rL[c*3+1]*od[720+144+d] + rL[c*3+2]*od[720+288+d] + tL[c];
      int h = d/12, pp = d - 12*h;
      if (pp < 4) kP[((size_t)h*768 + n)*12 + pp*3 + c] = f2us(g);
      else        vP[((size_t)h*768 + n)*24 + (pp-4)*3 + c] = f2us(g);
    }
  }
}

// ---------------- K2: fused attention ----------------
// Identical structure to the proven round-0 kernel; ONLY the K/V global
// addressing changed to head-major (contiguous per-lane rows -> ~5x fewer
// cache-line transactions). No staging, no prefetch registers.
__global__ __launch_bounds__(256) void k_attn(
    const float* __restrict__ in2d, const float* __restrict__ rot,
    const float* __restrict__ trans, const float* __restrict__ w2d,
    const float* __restrict__ b2d, const float* __restrict__ tpw,
    float* ws){
  __shared__ __align__(16) float Ld[768*12];   // 36,864 B
  __shared__ float invL[12];
  __shared__ float pwS[12], b2S[12];
  __shared__ float rotL[9], transL[3];
  const int i = blockIdx.x, t = threadIdx.x;
  const float* qs_f = ws + OFF_QS + i*192;     // block-uniform -> s_load
  const float* qp_f = ws + OFF_QP + i*144;
  const ushort* ws16 = reinterpret_cast<const ushort*>(ws);
  const ushort* kSp = ws16 + US_KS;
  const ushort* vSp = ws16 + US_VS;
  const ushort* kPp = ws16 + US_KP;
  const ushort* vPp = ws16 + US_VP;
  if (t < 9) rotL[t] = rot[i*9+t];
  if (t >= 9 && t < 12) transL[t-9] = trans[i*3+t-9];
  if (t < 12){
    b2S[t] = b2d[t];
    pwS[t] = -0.5f * PW_CONST * log1pf(__expf(tpw[t]));
  }
  __syncthreads();
  // ---- Phase A ----
  for (int j = t; j < 768; j += 256){
    float acc12[12];
    #pragma unroll
    for (int h = 0; h < 12; ++h) acc12[h] = b2S[h];
    const float4* p2 = reinterpret_cast<const float4*>(in2d + (size_t)(i*768 + j)*128);
    #pragma unroll 4
    for (int c4 = 0; c4 < 32; ++c4){
      float4 u = p2[c4];
      const float* wr = w2d + c4*48;           // lane-uniform -> scalar loads
      #pragma unroll
      for (int h = 0; h < 12; ++h)
        acc12[h] += u.x*wr[h] + u.y*wr[12+h] + u.z*wr[24+h] + u.w*wr[36+h];
    }
    #pragma unroll
    for (int h = 0; h < 12; ++h){
      // head-major: lane j reads its contiguous 32B row (16B-aligned)
      const uint4* pk = reinterpret_cast<const uint4*>(kSp + ((size_t)h*768 + j)*16);
      uint4 a = pk[0], b = pk[1];
      float kf[16]; up8(a, kf); up8(b, kf+8);
      float qk = 0.f;
      const float* qr = qs_f + h*16;           // uniform
      #pragma unroll
      for (int d = 0; d < 16; ++d) qk += qr[d] * kf[d];
      // head-major: contiguous 24B row (8B-aligned)
      const uint2* pp = reinterpret_cast<const uint2*>(kPp + ((size_t)h*768 + j)*12);
      uint2 c0 = pp[0], c1 = pp[1], c2 = pp[2];
      float pf[12] = {blo(c0.x),bhi(c0.x),blo(c0.y),bhi(c0.y),
                      blo(c1.x),bhi(c1.x),blo(c1.y),bhi(c1.y),
                      blo(c2.x),bhi(c2.x),blo(c2.y),bhi(c2.y)};
      const float* qpr = qp_f + h*12;          // uniform
      float d2 = 0.f;
      #pragma unroll
      for (int e = 0; e < 12; ++e){ float dd = qpr[e] - pf[e]; d2 += dd*dd; }
      acc12[h] = acc12[h]*RSQRT3 + qk + pwS[h]*d2;
    }
    float4* lp = reinterpret_cast<float4*>(&Ld[j*12]);
    lp[0] = make_float4(acc12[0], acc12[1], acc12[2],  acc12[3]);
    lp[1] = make_float4(acc12[4], acc12[5], acc12[6],  acc12[7]);
    lp[2] = make_float4(acc12[8], acc12[9], acc12[10], acc12[11]);
  }
  __syncthreads();
  // ---- Phase B: wave w owns heads {w, w+4, w+8} (disjoint LDS columns) ----
  const int wave = t >> 6, lane = t & 63;
  float invReg[3];
  #pragma unroll
  for (int s = 0; s < 3; ++s){
    int h = wave + s*4;
    float m = -1e30f;
    for (int k = 0; k < 12; ++k) m = fmaxf(m, Ld[(lane + (k<<6))*12 + h]);
    #pragma unroll
    for (int o = 32; o > 0; o >>= 1) m = fmaxf(m, __shfl_xor(m, o));
    float sum = 0.f;
    for (int k = 0; k < 12; ++k){
      int idx = (lane + (k<<6))*12 + h;
      float e = __expf(fminf(Ld[idx] - m, 0.f));
      Ld[idx] = e;
      sum += e;
    }
    #pragma unroll
    for (int o = 32; o > 0; o >>= 1) sum += __shfl_xor(sum, o);
    float inv = 1.f / sum;
    invReg[s] = inv;
    if (lane == 0) invL[h] = inv;
  }
  // ---- Phase C (same wave->head ownership; no barrier needed) ----
  float* finp = ws + OFF_FINP + (size_t)i*576;
  #pragma unroll
  for (int s = 0; s < 3; ++s){
    int h = wave + s*4;
    float accS[16], accP[24];
    #pragma unroll
    for (int d = 0; d < 16; ++d) accS[d] = 0.f;
    #pragma unroll
    for (int d = 0; d < 24; ++d) accP[d] = 0.f;
    for (int it = 0; it < 12; ++it){
      int jj = lane + (it<<6);
      float e = Ld[jj*12 + h];
      // head-major: contiguous 32B row (16B-aligned)
      const uint4* pv = reinterpret_cast<const uint4*>(vSp + ((size_t)h*768 + jj)*16);
      uint4 a = pv[0], b = pv[1];
      float vf[16]; up8(a, vf); up8(b, vf+8);
      #pragma unroll
      for (int d = 0; d < 16; ++d) accS[d] += e * vf[d];
      // head-major: contiguous 48B row (16B-aligned)
      const uint4* pq = reinterpret_cast<const uint4*>(vPp + ((size_t)h*768 + jj)*24);
      uint4 q0 = pq[0], q1 = pq[1], q2 = pq[2];
      float pf[24]; up8(q0, pf); up8(q1, pf+8); up8(q2, pf+16);
      #pragma unroll
      for (int d = 0; d < 24; ++d) accP[d] += e * pf[d];
    }
    #pragma unroll
    for (int o2 = 32; o2 > 0; o2 >>= 1){
      #pragma unroll
      for (int d = 0; d < 16; ++d) accS[d] += __shfl_xor(accS[d], o2);
      #pragma unroll
      for (int d = 0; d < 24; ++d) accP[d] += __shfl_xor(accP[d], o2);
    }
    if (lane == 0){
      float inv = invReg[s];
      #pragma unroll
      for (int d = 0; d < 16; ++d) finp[h*16 + d] = accS[d]*inv;
      #pragma unroll
      for (int p = 0; p < 8; ++p){
        float gx = accP[p*3+0]*inv - transL[0];
        float gy = accP[p*3+1]*inv - transL[1];
        float gz = accP[p*3+2]*inv - transL[2];
        float n2 = 1e-8f;
        #pragma unroll
        for (int c = 0; c < 3; ++c){
          float r = rotL[c]*gx + rotL[3+c]*gy + rotL[6+c]*gz;  // rot^T
          finp[192 + c*96 + h*8 + p] = r;
          n2 += r*r;
        }
        finp[480 + h*8 + p] = sqrtf(n2);
      }
    }
  }
  __syncthreads();   // all exp columns + invL visible everywhere
  // ---- Phase D: a_over_2d. thread = (channel pair cp, j-quarter jg) ----
  {
    const int cp = t & 63, jg = t >> 6;
    float acc[24];
    #pragma unroll
    for (int d = 0; d < 24; ++d) acc[d] = 0.f;
    const float* rowp = in2d + (size_t)i*768*128 + 2*cp;
    const int j0 = jg*192;
    for (int j = j0; j < j0 + 192; ++j){
      float2 x2 = *reinterpret_cast<const float2*>(rowp + (size_t)j*128);
      float x0 = x2.x, x1 = x2.y;
      const float4* lp = reinterpret_cast<const float4*>(&Ld[j*12]);  // wave-uniform -> broadcast
      float4 e0 = lp[0], e1 = lp[1], e2 = lp[2];
      acc[0] += e0.x*x0;  acc[1] += e0.x*x1;
      acc[2] += e0.y*x0;  acc[3] += e0.y*x1;
      acc[4] += e0.z*x0;  acc[5] += e0.z*x1;
      acc[6] += e0.w*x0;  acc[7] += e0.w*x1;
      acc[8] += e1.x*x0;  acc[9] += e1.x*x1;
      acc[10]+= e1.y*x0;  acc[11]+= e1.y*x1;
      acc[12]+= e1.z*x0;  acc[13]+= e1.z*x1;
      acc[14]+= e1.w*x0;  acc[15]+= e1.w*x1;
      acc[16]+= e2.x*x0;  acc[17]+= e2.x*x1;
      acc[18]+= e2.y*x0;  acc[19]+= e2.y*x1;
      acc[20]+= e2.z*x0;  acc[21]+= e2.z*x1;
      acc[22]+= e2.w*x0;  acc[23]+= e2.w*x1;
    }
    __syncthreads();   // all Ld reads done; reuse as reduction scratch
    float* LdR = Ld;   // [3][64][25] = 4800 floats < 9216
    if (jg > 0){
      #pragma unroll
      for (int d = 0; d < 24; ++d) LdR[((jg-1)*64 + cp)*25 + d] = acc[d];
    }
    __syncthreads();
    if (jg == 0){
      ushort* fa16 = reinterpret_cast<ushort*>(ws) + US_FA + (size_t)i*1536;
      float invA[12];
      #pragma unroll
      for (int h = 0; h < 12; ++h) invA[h] = invL[h];
      #pragma unroll
      for (int h = 0; h < 12; ++h){
        float a0 = acc[2*h]   + LdR[cp*25 + 2*h]   + LdR[(64+cp)*25 + 2*h]   + LdR[(128+cp)*25 + 2*h];
        float a1 = acc[2*h+1] + LdR[cp*25 + 2*h+1] + LdR[(64+cp)*25 + 2*h+1] + LdR[(128+cp)*25 + 2*h+1];
        fa16[h*128 + 2*cp]     = f2us(a0 * invA[h]);
        fa16[h*128 + 2*cp + 1] = f2us(a1 * invA[h]);
      }
    }
  }
}

// ---------------- K3: output GEMM (768x2112 @ 2112x384, fp32 out) ----------------
__global__ __launch_bounds__(128) void k_out(const float* __restrict__ out_w,
                                             const float* __restrict__ out_b,
                                             const float* ws,
                                             float* __restrict__ out){
  __shared__ float Arow[4*2112];   // 33,792 B
  const int o = blockIdx.x*128 + threadIdx.x;
  const int ib = blockIdx.y*4;
  const ushort* ws16 = reinterpret_cast<const ushort*>(ws);
  #pragma unroll
  for (int r = 0; r < 4; ++r){
    const float* fp = ws + OFF_FINP + (size_t)(ib+r)*576;
    for (int k = threadIdx.x; k < 576; k += 128) Arow[r*2112 + k] = fp[k];
    const ushort* fa = ws16 + US_FA + (size_t)(ib+r)*1536;
    for (int k = threadIdx.x; k < 1536; k += 128) Arow[r*2112 + 576 + k] = bf1(fa[k]);
  }
  __syncthreads();
  float bc = out_b[o];
  float acc0 = bc, acc1 = bc, acc2 = bc, acc3 = bc;
  const float* wp = out_w + o;
  #pragma unroll 8
  for (int k = 0; k < 2112; ++k){
    float w = wp[(size_t)k*384];
    acc0 += Arow[k]*w; acc1 += Arow[2112+k]*w; acc2 += Arow[4224+k]*w; acc3 += Arow[6336+k]*w;
  }
  // diagnostic sanitize: NaN/Inf -> 1e6 sentinel (never triggers when healthy)
  if (!(fabsf(acc0) < 1e30f)) acc0 = 1e6f;
  if (!(fabsf(acc1) < 1e30f)) acc1 = 1e6f;
  if (!(fabsf(acc2) < 1e30f)) acc2 = 1e6f;
  if (!(fabsf(acc3) < 1e30f)) acc3 = 1e6f;
  out[(ib+0)*384 + o] = acc0;
  out[(ib+1)*384 + o] = acc1;
  out[(ib+2)*384 + o] = acc2;
  out[(ib+3)*384 + o] = acc3;
}

extern "C" void kernel_launch(void* const* d_in, const int* in_sizes, int n_in,
                              void* d_out, int out_size, void* d_ws, size_t ws_size,
                              hipStream_t stream){
  const float* in1d  = (const float*)d_in[0];
  const float* in2d  = (const float*)d_in[1];
  const float* rot   = (const float*)d_in[2];
  const float* trans = (const float*)d_in[3];
  const float* qsw   = (const float*)d_in[4];
  const float* qsb   = (const float*)d_in[5];
  const float* kvsw  = (const float*)d_in[6];
  const float* kvsb  = (const float*)d_in[7];
  const float* qpw   = (const float*)d_in[8];
  const float* qpb   = (const float*)d_in[9];
  const float* kvpw  = (const float*)d_in[10];
  const float* kvpb  = (const float*)d_in[11];
  const float* tpw   = (const float*)d_in[12];
  const float* w2d   = (const float*)d_in[13];
  const float* b2d   = (const float*)d_in[14];
  const float* outw  = (const float*)d_in[15];
  const float* outb  = (const float*)d_in[16];
  float* ws = (float*)d_ws;

  k_proj<<<dim3(192), dim3(256), 0, stream>>>(rot, trans, qsw, qsb, kvsw, kvsb,
                                              qpw, qpb, kvpw, kvpb, in1d, ws);
  k_attn<<<dim3(768), dim3(256), 0, stream>>>(in2d, rot, trans, w2d, b2d, tpw, ws);
  k_out<<<dim3(3,192), dim3(128), 0, stream>>>(outw, outb, ws, (float*)d_out);
}

// Round 5
// 752.765 us; speedup vs baseline: 1.2819x; 1.1343x over previous
//
#include <hip/hip_runtime.h>
#include <hip/hip_bf16.h>

typedef unsigned int uint;
typedef unsigned short ushort;

// ---- problem constants ----
#define SCALAR_W 0.14433756729740643f   // 1/sqrt(3*16)
#define PW_CONST 0.13608276348795434f   // 1/sqrt(3*4*4.5)
#define RSQRT3   0.57735026918962576f   // attn2d scale

// ---- ws layout ----  total 6,414,336 bytes (unchanged offsets)
#define OFF_QS    0                     // [768][12][16] fp32  q*scalar_w
#define OFF_QP    147456                // [768][48][3] fp32   q points (global frame)
#define OFF_FINP  258048                // [768][576] fp32     final cols 0..575
// ushort-index offsets (HEAD-MAJOR tables)
#define US_KS     1400832               // [12][768][16] bf16  scalar K
#define US_VS     1548288               // [12][768][16] bf16  scalar V
#define US_KP     1695744               // [12][768][12] bf16  point K
#define US_VP     1806336               // [12][768][24] bf16  point V
#define US_FA     2027520               // [768][1536] bf16    final cols 576..2111

__device__ __forceinline__ float blo(uint u){ return __uint_as_float(u << 16); }
__device__ __forceinline__ float bhi(uint u){ return __uint_as_float(u & 0xffff0000u); }
__device__ __forceinline__ float bf1(ushort s){ return __uint_as_float(((uint)s) << 16); }
__device__ __forceinline__ void up8(uint4 u, float* f){
  f[0]=blo(u.x); f[1]=bhi(u.x); f[2]=blo(u.y); f[3]=bhi(u.y);
  f[4]=blo(u.z); f[5]=bhi(u.z); f[6]=blo(u.w); f[7]=bhi(u.w);
}
__device__ __forceinline__ ushort f2us(float f){
  return (ushort)__bfloat16_as_ushort(__float2bfloat16(f));
}

// ---------------- K1: projections (768 blocks, 3/CU) + out bias init ----------------
__global__ __launch_bounds__(256) void k_proj(
    const float* __restrict__ rot, const float* __restrict__ trans,
    const float* __restrict__ qsw, const float* __restrict__ qsb,
    const float* __restrict__ kvsw, const float* __restrict__ kvsb,
    const float* __restrict__ qpw, const float* __restrict__ qpb,
    const float* __restrict__ kvpw, const float* __restrict__ kvpb,
    const float* __restrict__ in1d, const float* __restrict__ outb,
    float* ws, float* __restrict__ out){
  __shared__ float orow[1152];
  __shared__ float rotL[9], transL[3];
  const int n = blockIdx.x, t = threadIdx.x;
  const float* arow = in1d + (size_t)n*384;            // block-uniform -> s_load
  if (t < 9) rotL[t] = rot[n*9+t];
  if (t >= 9 && t < 12) transL[t-9] = trans[n*3+t-9];
  // bias init for k_out's atomic accumulation (out fully re-accumulated each launch)
  out[(size_t)n*384 + t] = outb[t];
  if (t < 128) out[(size_t)n*384 + 256 + t] = outb[256 + t];
  #pragma unroll
  for (int r = 0; r < 3; ++r){
    int idx = t + 256*r;
    if (idx < 576){
      int o = idx*2;
      const float* w; const float* bp; int ncol, col;
      if (o < 192){ w=qsw; ncol=192; col=o; bp=qsb+col; }
      else if (o < 576){ w=kvsw; ncol=384; col=o-192; bp=kvsb+col; }
      else if (o < 720){ w=qpw; ncol=144; col=o-576; bp=qpb+col; }
      else { w=kvpw; ncol=432; col=o-720; bp=kvpb+col; }
      float2 b2 = *reinterpret_cast<const float2*>(bp);
      float a0 = b2.x, a1 = b2.y;
      const float* wp = w + col;
      #pragma unroll 4
      for (int k = 0; k < 384; ++k){
        float2 u = *reinterpret_cast<const float2*>(wp + (size_t)k*ncol);
        float av = arow[k];
        a0 += av * u.x;
        a1 += av * u.y;
      }
      orow[o] = a0; orow[o+1] = a1;
    }
  }
  __syncthreads();
  float* qs_f = ws + OFF_QS;
  float* qp_f = ws + OFF_QP;
  ushort* ws16 = reinterpret_cast<ushort*>(ws);
  ushort* kS = ws16 + US_KS;
  ushort* vS = ws16 + US_VS;
  ushort* kP = ws16 + US_KP;
  ushort* vP = ws16 + US_VP;
  if (t < 192) qs_f[n*192 + t] = orow[t] * SCALAR_W;
  for (int x = t; x < 384; x += 256){
    int h = x >> 5, d = x & 31;
    float v = orow[192 + x];
    if (d < 16) kS[((size_t)h*768 + n)*16 + d] = f2us(v);
    else        vS[((size_t)h*768 + n)*16 + (d-16)] = f2us(v);
  }
  for (int x = t; x < 144; x += 256){
    int d = x/3, c = x - 3*d;
    float g = rotL[c*3]*orow[576+d] + rotL[c*3+1]*orow[576+48+d] + rotL[c*3+2]*orow[576+96+d] + transL[c];
    qp_f[n*144 + d*3 + c] = g;
  }
  for (int x = t; x < 432; x += 256){
    int d = x/3, c = x - 3*d;
    float g = rotL[c*3]*orow[720+d] + rotL[c*3+1]*orow[720+144+d] + rotL[c*3+2]*orow[720+288+d] + transL[c];
    int h = d/12, pp = d - 12*h;
    if (pp < 4) kP[((size_t)h*768 + n)*12 + pp*3 + c] = f2us(g);
    else        vP[((size_t)h*768 + n)*24 + (pp-4)*3 + c] = f2us(g);
  }
}

// ---------------- K2: fused attention, HEAD-SPLIT (2 blocks per i, 6 heads each) ----------------
// grid 1536: i = bid>>1, h0 = (bid&1)*6.  Ld halves to [768][6] -> 18.4 KB LDS,
// ~6 resident blocks/CU (vs 3).  Same phase structure as the proven round-4 kernel.
__global__ __launch_bounds__(256) void k_attn(
    const float* __restrict__ in2d, const float* __restrict__ rot,
    const float* __restrict__ trans, const float* __restrict__ w2d,
    const float* __restrict__ b2d, const float* __restrict__ tpw,
    float* ws){
  __shared__ __align__(16) float Ld[768*6];    // 18,432 B
  __shared__ float invL[6];
  __shared__ float pwS[6], b2S[6];
  __shared__ float rotL[9], transL[3];
  const int bid = blockIdx.x, t = threadIdx.x;
  const int i = bid >> 1, h0 = (bid & 1)*6;
  const float* qs_f = ws + OFF_QS + i*192;     // block-uniform -> s_load
  const float* qp_f = ws + OFF_QP + i*144;
  const ushort* ws16 = reinterpret_cast<const ushort*>(ws);
  const ushort* kSp = ws16 + US_KS;
  const ushort* vSp = ws16 + US_VS;
  const ushort* kPp = ws16 + US_KP;
  const ushort* vPp = ws16 + US_VP;
  if (t < 9) rotL[t] = rot[i*9+t];
  if (t >= 9 && t < 12) transL[t-9] = trans[i*3+t-9];
  if (t < 6){
    b2S[t] = b2d[h0 + t];
    pwS[t] = -0.5f * PW_CONST * log1pf(__expf(tpw[h0 + t]));
  }
  __syncthreads();
  // ---- Phase A: logits for 6 heads ----
  for (int j = t; j < 768; j += 256){
    float acc6[6];
    #pragma unroll
    for (int h = 0; h < 6; ++h) acc6[h] = b2S[h];
    const float4* p2 = reinterpret_cast<const float4*>(in2d + (size_t)(i*768 + j)*128);
    #pragma unroll 4
    for (int c4 = 0; c4 < 32; ++c4){
      float4 u = p2[c4];
      const float* wr = w2d + c4*48 + h0;      // lane-uniform -> scalar loads
      #pragma unroll
      for (int h = 0; h < 6; ++h)
        acc6[h] += u.x*wr[h] + u.y*wr[12+h] + u.z*wr[24+h] + u.w*wr[36+h];
    }
    #pragma unroll
    for (int h = 0; h < 6; ++h){
      const int hg = h0 + h;
      const uint4* pk = reinterpret_cast<const uint4*>(kSp + ((size_t)hg*768 + j)*16);
      uint4 a = pk[0], b = pk[1];
      float kf[16]; up8(a, kf); up8(b, kf+8);
      float qk = 0.f;
      const float* qr = qs_f + hg*16;          // uniform
      #pragma unroll
      for (int d = 0; d < 16; ++d) qk += qr[d] * kf[d];
      const uint2* pp = reinterpret_cast<const uint2*>(kPp + ((size_t)hg*768 + j)*12);
      uint2 c0 = pp[0], c1 = pp[1], c2 = pp[2];
      float pf[12] = {blo(c0.x),bhi(c0.x),blo(c0.y),bhi(c0.y),
                      blo(c1.x),bhi(c1.x),blo(c1.y),bhi(c1.y),
                      blo(c2.x),bhi(c2.x),blo(c2.y),bhi(c2.y)};
      const float* qpr = qp_f + hg*12;         // uniform
      float d2 = 0.f;
      #pragma unroll
      for (int e = 0; e < 12; ++e){ float dd = qpr[e] - pf[e]; d2 += dd*dd; }
      acc6[h] = acc6[h]*RSQRT3 + qk + pwS[h]*d2;
    }
    float2* lp = reinterpret_cast<float2*>(&Ld[j*6]);
    lp[0] = make_float2(acc6[0], acc6[1]);
    lp[1] = make_float2(acc6[2], acc6[3]);
    lp[2] = make_float2(acc6[4], acc6[5]);
  }
  __syncthreads();
  // ---- Phase B: waves 0,1 own 2 heads {w,w+4}; waves 2,3 own 1 head {w} ----
  const int wave = t >> 6, lane = t & 63;
  float invReg[2];
  #pragma unroll
  for (int s = 0; s < 2; ++s){
    int h = wave + s*4;
    if (h < 6){
      float m = -1e30f;
      for (int k = 0; k < 12; ++k) m = fmaxf(m, Ld[(lane + (k<<6))*6 + h]);
      #pragma unroll
      for (int o = 32; o > 0; o >>= 1) m = fmaxf(m, __shfl_xor(m, o));
      float sum = 0.f;
      for (int k = 0; k < 12; ++k){
        int idx = (lane + (k<<6))*6 + h;
        float e = __expf(fminf(Ld[idx] - m, 0.f));
        Ld[idx] = e;
        sum += e;
      }
      #pragma unroll
      for (int o = 32; o > 0; o >>= 1) sum += __shfl_xor(sum, o);
      float inv = 1.f / sum;
      invReg[s] = inv;
      if (lane == 0) invL[h] = inv;
    }
  }
  // ---- Phase C (same wave->head ownership) ----
  float* finp = ws + OFF_FINP + (size_t)i*576;
  #pragma unroll
  for (int s = 0; s < 2; ++s){
    int h = wave + s*4;
    if (h >= 6) break;
    const int hg = h0 + h;
    float accS[16], accP[24];
    #pragma unroll
    for (int d = 0; d < 16; ++d) accS[d] = 0.f;
    #pragma unroll
    for (int d = 0; d < 24; ++d) accP[d] = 0.f;
    for (int it = 0; it < 12; ++it){
      int jj = lane + (it<<6);
      float e = Ld[jj*6 + h];
      const uint4* pv = reinterpret_cast<const uint4*>(vSp + ((size_t)hg*768 + jj)*16);
      uint4 a = pv[0], b = pv[1];
      float vf[16]; up8(a, vf); up8(b, vf+8);
      #pragma unroll
      for (int d = 0; d < 16; ++d) accS[d] += e * vf[d];
      const uint4* pq = reinterpret_cast<const uint4*>(vPp + ((size_t)hg*768 + jj)*24);
      uint4 q0 = pq[0], q1 = pq[1], q2 = pq[2];
      float pf[24]; up8(q0, pf); up8(q1, pf+8); up8(q2, pf+16);
      #pragma unroll
      for (int d = 0; d < 24; ++d) accP[d] += e * pf[d];
    }
    #pragma unroll
    for (int o2 = 32; o2 > 0; o2 >>= 1){
      #pragma unroll
      for (int d = 0; d < 16; ++d) accS[d] += __shfl_xor(accS[d], o2);
      #pragma unroll
      for (int d = 0; d < 24; ++d) accP[d] += __shfl_xor(accP[d], o2);
    }
    if (lane == 0){
      float inv = invReg[s];
      #pragma unroll
      for (int d = 0; d < 16; ++d) finp[hg*16 + d] = accS[d]*inv;
      #pragma unroll
      for (int p = 0; p < 8; ++p){
        float gx = accP[p*3+0]*inv - transL[0];
        float gy = accP[p*3+1]*inv - transL[1];
        float gz = accP[p*3+2]*inv - transL[2];
        float n2 = 1e-8f;
        #pragma unroll
        for (int c = 0; c < 3; ++c){
          float r = rotL[c]*gx + rotL[3+c]*gy + rotL[6+c]*gz;  // rot^T
          finp[192 + c*96 + hg*8 + p] = r;
          n2 += r*r;
        }
        finp[480 + hg*8 + p] = sqrtf(n2);
      }
    }
  }
  __syncthreads();   // all exp columns + invL visible everywhere
  // ---- Phase D: a_over_2d for 6 heads ----
  {
    const int cp = t & 63, jg = t >> 6;
    float acc[12];
    #pragma unroll
    for (int d = 0; d < 12; ++d) acc[d] = 0.f;
    const float* rowp = in2d + (size_t)i*768*128 + 2*cp;
    const int j0 = jg*192;
    for (int j = j0; j < j0 + 192; ++j){
      float2 x2 = *reinterpret_cast<const float2*>(rowp + (size_t)j*128);
      float x0 = x2.x, x1 = x2.y;
      const float2* lp = reinterpret_cast<const float2*>(&Ld[j*6]);  // wave-uniform -> broadcast
      float2 e0 = lp[0], e1 = lp[1], e2 = lp[2];
      acc[0] += e0.x*x0;  acc[1] += e0.x*x1;
      acc[2] += e0.y*x0;  acc[3] += e0.y*x1;
      acc[4] += e1.x*x0;  acc[5] += e1.x*x1;
      acc[6] += e1.y*x0;  acc[7] += e1.y*x1;
      acc[8] += e2.x*x0;  acc[9] += e2.x*x1;
      acc[10]+= e2.y*x0;  acc[11]+= e2.y*x1;
    }
    __syncthreads();   // all Ld reads done; reuse as reduction scratch
    float* LdR = Ld;   // [3][64][13] = 2496 floats < 4608
    if (jg > 0){
      #pragma unroll
      for (int d = 0; d < 12; ++d) LdR[((jg-1)*64 + cp)*13 + d] = acc[d];
    }
    __syncthreads();
    if (jg == 0){
      ushort* fa16 = reinterpret_cast<ushort*>(ws) + US_FA + (size_t)i*1536;
      float invA[6];
      #pragma unroll
      for (int h = 0; h < 6; ++h) invA[h] = invL[h];
      #pragma unroll
      for (int h = 0; h < 6; ++h){
        float a0 = acc[2*h]   + LdR[cp*13 + 2*h]   + LdR[(64+cp)*13 + 2*h]   + LdR[(128+cp)*13 + 2*h];
        float a1 = acc[2*h+1] + LdR[cp*13 + 2*h+1] + LdR[(64+cp)*13 + 2*h+1] + LdR[(128+cp)*13 + 2*h+1];
        fa16[(h0+h)*128 + 2*cp]     = f2us(a0 * invA[h]);
        fa16[(h0+h)*128 + 2*cp + 1] = f2us(a1 * invA[h]);
      }
    }
  }
}

// ---------------- K3: output GEMM, k-split x4 + atomic accumulate ----------------
// grid (3, 192, 4): 2304 blocks (~9/CU) vs 576.  Latency chain 2112 -> 528.
// out pre-initialized with bias by k_proj.
__global__ __launch_bounds__(128) void k_out(const float* __restrict__ out_w,
                                             const float* ws,
                                             float* __restrict__ out){
  __shared__ float Arow[4*528];   // 8,448 B
  const int o = blockIdx.x*128 + threadIdx.x;
  const int ib = blockIdx.y*4;
  const int k0 = blockIdx.z*528;
  const ushort* ws16 = reinterpret_cast<const ushort*>(ws);
  #pragma unroll
  for (int r = 0; r < 4; ++r){
    const float* fp = ws + OFF_FINP + (size_t)(ib+r)*576;
    const ushort* fa = ws16 + US_FA + (size_t)(ib+r)*1536;
    for (int k = threadIdx.x; k < 528; k += 128){
      int col = k0 + k;
      Arow[r*528 + k] = (col < 576) ? fp[col] : bf1(fa[col - 576]);
    }
  }
  __syncthreads();
  float a0 = 0.f, a1 = 0.f, a2 = 0.f, a3 = 0.f;
  const float* wp = out_w + (size_t)k0*384 + o;
  #pragma unroll 8
  for (int k = 0; k < 528; ++k){
    float w = wp[(size_t)k*384];
    a0 += Arow[k]*w; a1 += Arow[528+k]*w; a2 += Arow[1056+k]*w; a3 += Arow[1584+k]*w;
  }
  atomicAdd(&out[(size_t)(ib+0)*384 + o], a0);
  atomicAdd(&out[(size_t)(ib+1)*384 + o], a1);
  atomicAdd(&out[(size_t)(ib+2)*384 + o], a2);
  atomicAdd(&out[(size_t)(ib+3)*384 + o], a3);
}

extern "C" void kernel_launch(void* const* d_in, const int* in_sizes, int n_in,
                              void* d_out, int out_size, void* d_ws, size_t ws_size,
                              hipStream_t stream){
  const float* in1d  = (const float*)d_in[0];
  const float* in2d  = (const float*)d_in[1];
  const float* rot   = (const float*)d_in[2];
  const float* trans = (const float*)d_in[3];
  const float* qsw   = (const float*)d_in[4];
  const float* qsb   = (const float*)d_in[5];
  const float* kvsw  = (const float*)d_in[6];
  const float* kvsb  = (const float*)d_in[7];
  const float* qpw   = (const float*)d_in[8];
  const float* qpb   = (const float*)d_in[9];
  const float* kvpw  = (const float*)d_in[10];
  const float* kvpb  = (const float*)d_in[11];
  const float* tpw   = (const float*)d_in[12];
  const float* w2d   = (const float*)d_in[13];
  const float* b2d   = (const float*)d_in[14];
  const float* outw  = (const float*)d_in[15];
  const float* outb  = (const float*)d_in[16];
  float* ws = (float*)d_ws;

  k_proj<<<dim3(768), dim3(256), 0, stream>>>(rot, trans, qsw, qsb, kvsw, kvsb,
                                              qpw, qpb, kvpw, kvpb, in1d, outb,
                                              ws, (float*)d_out);
  k_attn<<<dim3(1536), dim3(256), 0, stream>>>(in2d, rot, trans, w2d, b2d, tpw, ws);
  k_out<<<dim3(3,192,4), dim3(128), 0, stream>>>(outw, ws, (float*)d_out);
}